// Round 18
// baseline (816.128 us; speedup 1.0000x reference)
//
#include <hip/hip_runtime.h>
#include <math.h>

#define B_ 2
#define S_ 2048
#define HD 2048
#define NH_ 16
#define DH_ 128
#define FF_ 8192
#define MROWS (B_*S_)   // 4096
#define LDQ 6144        // fused qkv row stride

typedef __attribute__((ext_vector_type(8))) short bf16x8;
typedef __attribute__((ext_vector_type(4))) short s16x4;
typedef __attribute__((ext_vector_type(4))) float f32x4;

static __device__ __forceinline__ unsigned short f2bf(float f) {
    unsigned u = __float_as_uint(f);
    u += 0x7fffu + ((u >> 16) & 1u);   // round-to-nearest-even
    return (unsigned short)(u >> 16);
}

// RNA (round-half-away) — 2 ops; used only for P (>=0, differs from RNE at midpoints)
static __device__ __forceinline__ unsigned short f2bf_rna(float f) {
    return (unsigned short)((__float_as_uint(f) + 0x8000u) >> 16);
}

static __device__ __forceinline__ void gload_lds16(const void* g, void* lds) {
    __builtin_amdgcn_global_load_lds((const __attribute__((address_space(1))) void*)g,
                                     (__attribute__((address_space(3))) void*)lds, 16, 0, 0);
}

// ---------------- weight fp32 -> bf16 transpose: Wt[N][K] = bf16(W[K][N]) ----------------
__global__ __launch_bounds__(256) void trcvt_kernel(const float* __restrict__ W,
        short* __restrict__ Wt, int K, int N) {
    __shared__ float tile[64][65];
    int t = threadIdx.x;
    int tr = t >> 4;              // 0..15
    int tc4 = (t & 15) * 4;       // 0,4,..,60
    int r0 = blockIdx.y * 64, c0 = blockIdx.x * 64;   // r0: k, c0: n
    #pragma unroll
    for (int i = 0; i < 4; i++) {
        float4 v = *(const float4*)(W + (size_t)(r0 + tr + 16*i) * N + c0 + tc4);
        tile[tr + 16*i][tc4 + 0] = v.x;
        tile[tr + 16*i][tc4 + 1] = v.y;
        tile[tr + 16*i][tc4 + 2] = v.z;
        tile[tr + 16*i][tc4 + 3] = v.w;
    }
    __syncthreads();
    #pragma unroll
    for (int i = 0; i < 4; i++) {
        int oc = tr + 16*i;       // n_local
        s16x4 o;
        o.x = (short)f2bf(tile[tc4 + 0][oc]);
        o.y = (short)f2bf(tile[tc4 + 1][oc]);
        o.z = (short)f2bf(tile[tc4 + 2][oc]);
        o.w = (short)f2bf(tile[tc4 + 3][oc]);
        *(s16x4*)(Wt + (size_t)(c0 + oc) * K + r0 + tc4) = o;
    }
}

// ---------------- V transpose: vT[(hd)*2 + b][s] = qkv[b*S+s][4096+hd] ----------------
__global__ __launch_bounds__(256) void vtrans_kernel(const short* __restrict__ qkv,
        short* __restrict__ vT) {
    __shared__ short tile[32][33];
    int t = threadIdx.x;
    int tx = t & 31, ty = t >> 5;
    int c0 = blockIdx.x * 32;          // hd
    int r0 = blockIdx.y * 32;          // s
    int b  = blockIdx.z;
    #pragma unroll
    for (int i = 0; i < 4; i++)
        tile[ty + 8*i][tx] = qkv[(size_t)(b*S_ + r0 + ty + 8*i) * LDQ + 4096 + c0 + tx];
    __syncthreads();
    #pragma unroll
    for (int i = 0; i < 4; i++)
        vT[((size_t)(c0 + ty + 8*i) * 2 + b) * S_ + r0 + tx] = tile[tx][ty + 8*i];
}

// ---------------- LayerNorm fp32 in -> bf16 out ----------------
__global__ __launch_bounds__(256) void ln_kernel(const float* __restrict__ x,
                const float* __restrict__ g, const float* __restrict__ b,
                short* __restrict__ out) {
    int row = blockIdx.x;
    const float* xr = x + (size_t)row * HD;
    short* orow = out + (size_t)row * HD;
    int t = threadIdx.x;

    float4 v0 = ((const float4*)xr)[t];
    float4 v1 = ((const float4*)xr)[t + 256];
    float s  = v0.x + v0.y + v0.z + v0.w + v1.x + v1.y + v1.z + v1.w;
    float ss = v0.x*v0.x + v0.y*v0.y + v0.z*v0.z + v0.w*v0.w
             + v1.x*v1.x + v1.y*v1.y + v1.z*v1.z + v1.w*v1.w;

    #pragma unroll
    for (int off = 1; off < 64; off <<= 1) {
        s  += __shfl_xor(s,  off, 64);
        ss += __shfl_xor(ss, off, 64);
    }
    __shared__ float ws_s[4], ws_q[4];
    int wid = t >> 6;
    if ((t & 63) == 0) { ws_s[wid] = s; ws_q[wid] = ss; }
    __syncthreads();
    s  = ws_s[0] + ws_s[1] + ws_s[2] + ws_s[3];
    ss = ws_q[0] + ws_q[1] + ws_q[2] + ws_q[3];

    float mu  = s * (1.0f / HD);
    float var = ss * (1.0f / HD) - mu * mu;
    float rs  = rsqrtf(var + 1e-5f);

    float4 g0 = ((const float4*)g)[t];
    float4 g1 = ((const float4*)g)[t + 256];
    float4 b0 = ((const float4*)b)[t];
    float4 b1 = ((const float4*)b)[t + 256];
    s16x4 o0, o1;
    o0.x = (short)f2bf((v0.x - mu) * rs * g0.x + b0.x);
    o0.y = (short)f2bf((v0.y - mu) * rs * g0.y + b0.y);
    o0.z = (short)f2bf((v0.z - mu) * rs * g0.z + b0.z);
    o0.w = (short)f2bf((v0.w - mu) * rs * g0.w + b0.w);
    o1.x = (short)f2bf((v1.x - mu) * rs * g1.x + b1.x);
    o1.y = (short)f2bf((v1.y - mu) * rs * g1.y + b1.y);
    o1.z = (short)f2bf((v1.z - mu) * rs * g1.z + b1.z);
    o1.w = (short)f2bf((v1.w - mu) * rs * g1.w + b1.w);
    ((s16x4*)orow)[t]       = o0;
    ((s16x4*)orow)[t + 256] = o1;
}

// =================== 128x128 ring-2 MFMA GEMM, BK=32 (32 KiB LDS -> ~5 blocks/CU) ===================
// C = epi(A[M][K] @ Bt[N][K]^T). 256 thr = 4 waves (2x2), per-wave out 64x64.
// Per iter (BK=32): stage(t+1)->buf^1 (4 gload_lds/thr), vmcnt(4) retires exactly
// tile t's loads, barrier, 8 ds_read_b128 + 16 MFMA, barrier (WAR-safe by ring).
// Rows are 64B = 4 chunks; swizzle: store source chunk c^(row&3) at linear pos c,
// read chunk l4^(lm&3) -> uniform 8 lanes per 4-bank group (r12-equivalent balance).
template<bool PATCH, bool OUTBF16, bool BIAS, bool RES, bool GELU>
__global__ __launch_bounds__(256, 4) void gemm128(
        const short* __restrict__ A, const short* __restrict__ Bt,
        const float* __restrict__ bias, const float* __restrict__ res,
        void* __restrict__ Cout, int M, int N, int K) {
    __shared__ __align__(16) char ldsA[2][128 * 64];   // 8 KB per buf
    __shared__ __align__(16) char ldsB[2][128 * 64];

    int tid = threadIdx.x;
    int wave = tid >> 6, lane = tid & 63;
    int l4 = lane >> 4, lm = lane & 15;
    int wm = wave >> 1, wn = wave & 1;

    int bid = blockIdx.x;
    int m0, n0;
    if constexpr (PATCH) {
        // grid must be 32 m-tiles x 16 n-tiles (M=4096, N=2048)
        int xcd = bid & 7, local = bid >> 3;
        m0 = ((xcd & 3) * 8 + (local & 7)) << 7;
        n0 = ((xcd >> 2) * 8 + (local >> 3)) << 7;
    } else {
        int nx = N >> 7;
        m0 = (bid / nx) << 7; n0 = (bid % nx) << 7;
    }

    const short* Atile = A + (size_t)m0 * K;
    const short* Btile = Bt + (size_t)n0 * K;
    const int NT = K >> 5;   // BK=32

    // stage one 128x32 tile per operand (512 chunks of 16B, 2/thread each)
    auto stage = [&](int t, int buf) {
        int tw = (t >= NT) ? t - NT : t;
        const short* gA = Atile + tw * 32;
        const short* gB = Btile + tw * 32;
        #pragma unroll
        for (int s = 0; s < 2; s++) {
            int n = (wave * 2 + s) * 64 + lane;
            int row = n >> 2, c = n & 3;
            int cs = c ^ (row & 3);
            gload_lds16(gA + (size_t)row * K + cs * 8, ldsA[buf] + n * 16);
            gload_lds16(gB + (size_t)row * K + cs * 8, ldsB[buf] + n * 16);
        }
    };

    // per-lane read chunk (lane-constant): l4 ^ (lm&3)
    int ch = (l4 ^ (lm & 3)) & 3;
    const char* pA = (const char*)ldsA + (wm * 64 + lm) * 64 + ch * 16;
    const char* pB = (const char*)ldsB + (wn * 64 + lm) * 64 + ch * 16;

    f32x4 acc[4][4] = {};

    stage(0, 0);
    for (int t = 0; t < NT; t++) {
        int buf = t & 1;
        stage(t + 1, buf ^ 1);
        asm volatile("s_waitcnt vmcnt(4)" ::: "memory");
        __builtin_amdgcn_s_barrier();
        __builtin_amdgcn_sched_barrier(0);
        size_t bo = (size_t)buf * 128 * 64;
        __builtin_amdgcn_s_setprio(1);
        bf16x8 av[4], bv[4];
        #pragma unroll
        for (int f = 0; f < 4; f++)
            av[f] = *(const bf16x8*)(pA + bo + f * 1024);
        #pragma unroll
        for (int nn = 0; nn < 4; nn++)
            bv[nn] = *(const bf16x8*)(pB + bo + nn * 1024);
        #pragma unroll
        for (int f = 0; f < 4; f++)
            #pragma unroll
            for (int nn = 0; nn < 4; nn++)
                acc[f][nn] = __builtin_amdgcn_mfma_f32_16x16x32_bf16(
                    av[f], bv[nn], acc[f][nn], 0, 0, 0);
        __builtin_amdgcn_s_setprio(0);
        __builtin_amdgcn_s_barrier();
    }
    asm volatile("s_waitcnt vmcnt(0)" ::: "memory");
    __builtin_amdgcn_s_barrier();

    #pragma unroll
    for (int nn = 0; nn < 4; nn++) {
        int colb = n0 + wn * 64 + nn * 16 + lm;
        float bvs = BIAS ? bias[colb] : 0.f;
        #pragma unroll
        for (int m = 0; m < 4; m++) {
            #pragma unroll
            for (int r = 0; r < 4; r++) {
                int row = m0 + wm * 64 + m * 16 + l4 * 4 + r;
                float v = acc[m][nn][r] + bvs;
                if (GELU) {
                    // tanh-form GELU as sigmoid: v*sigma(1.5957691(v+0.044715 v^3))
                    float y = 1.5957691f * (v + 0.044715f * v * v * v);
                    v = v / (1.0f + __expf(-y));
                }
                size_t off = (size_t)row * N + colb;
                if (RES) v += res[off];
                if (OUTBF16) ((short*)Cout)[off] = (short)f2bf(v);
                else         ((float*)Cout)[off] = v;
            }
        }
    }
}

// ---------------- MFMA flash attention (tile-max + MFMA row-sum + swizzled P) ----------------
__global__ __launch_bounds__(256) void attn_kernel(
        const short* __restrict__ qkv, const short* __restrict__ vT,
        const float* __restrict__ mask, short* __restrict__ ctx) {
    __shared__ __align__(16) short Ks[2][64*128];   // [kv][d], chunk-swizzled
    __shared__ __align__(16) short Vt[2][128*64];   // [d][kv], chunk-swizzled
    __shared__ __align__(16) short Ps[4][16*72];    // per-wave P, pitch 72, XOR-swizzled
    int t = threadIdx.x;
    int wave = t >> 6, lane = t & 63;
    int l4 = lane >> 4, lm = lane & 15;
    int q0 = blockIdx.x * 64, h = blockIdx.y, zb = blockIdx.z;
    const float scale = 0.08838834764831845f;  // 1/sqrt(128)
    const int NT = S_ / 64;                    // 32 tiles

    bf16x8 aq[4];
    {
        const short* qrow = qkv + (size_t)(zb*S_ + q0 + wave*16 + lm) * LDQ + h*DH_;
        #pragma unroll
        for (int ks = 0; ks < 4; ks++)
            aq[ks] = *(const bf16x8*)(qrow + ks*32 + l4*8);
    }
    bf16x8 onesb;
    #pragma unroll
    for (int i = 0; i < 8; i++) onesb[i] = (short)0x3F80;   // bf16 1.0

    auto stageKV = [&](int ti, int buf) {
        int tw = (ti >= NT) ? ti - NT : ti;
        int kv0 = tw * 64;
        #pragma unroll
        for (int L = 0; L < 4; L++) {
            int c = (wave*4 + L)*64 + lane;
            int krow = c >> 4, kc = c & 15;
            int ksrc = (kc & 8) | ((kc ^ (krow & 7)) & 7);
            gload_lds16(qkv + (size_t)(zb*S_ + kv0 + krow)*LDQ + 2048 + h*DH_ + ksrc*8,
                        (char*)Ks[buf] + c*16);
            int drow = c >> 3, dc = c & 7;
            int dsrc = dc ^ (drow & 7);
            gload_lds16(vT + ((size_t)(h*DH_ + drow)*2 + zb)*S_ + kv0 + dsrc*8,
                        (char*)Vt[buf] + c*16);
        }
    };

    float m_run = -INFINITY;
    f32x4 lsum = (f32x4){0.f, 0.f, 0.f, 0.f};
    f32x4 o[8];
    #pragma unroll
    for (int i = 0; i < 8; i++) o[i] = (f32x4){0.f, 0.f, 0.f, 0.f};

    stageKV(0, 0);
    for (int ti = 0; ti < NT; ti++) {
        int buf = ti & 1;
        int kv0 = ti * 64;
        stageKV(ti + 1, buf ^ 1);
        asm volatile("s_waitcnt vmcnt(8)" ::: "memory");
        __builtin_amdgcn_s_barrier();
        __builtin_amdgcn_sched_barrier(0);
        const char* Kb = (const char*)Ks[buf];
        const char* Vb = (const char*)Vt[buf];

        f32x4 s[4];
        #pragma unroll
        for (int nb = 0; nb < 4; nb++) s[nb] = (f32x4){0.f, 0.f, 0.f, 0.f};
        __builtin_amdgcn_s_setprio(1);
        #pragma unroll
        for (int nb = 0; nb < 4; nb++) {
            int row = nb*16 + lm;
            #pragma unroll
            for (int ks = 0; ks < 4; ks++) {
                bf16x8 bk = *(const bf16x8*)(Kb +
                              ((row*256 + ks*64 + l4*16) ^ ((row & 7) << 4)));
                s[nb] = __builtin_amdgcn_mfma_f32_16x16x32_bf16(aq[ks], bk, s[nb], 0, 0, 0);
            }
        }
        __builtin_amdgcn_s_setprio(0);

        float mk[4];
        #pragma unroll
        for (int nb = 0; nb < 4; nb++) mk[nb] = mask[(size_t)zb*S_ + kv0 + nb*16 + lm];

        // ---- tile-wide max + defer (wave-uniform m) ----
        float pv_[4][4];
        float vmax = -INFINITY;
        #pragma unroll
        for (int r = 0; r < 4; r++)
            #pragma unroll
            for (int nb = 0; nb < 4; nb++) {
                float v = fmaf(s[nb][r], scale, mk[nb]);
                pv_[r][nb] = v;
                vmax = fmaxf(vmax, v);
            }
        vmax = fmaxf(vmax, __shfl_xor(vmax, 1, 64));
        vmax = fmaxf(vmax, __shfl_xor(vmax, 2, 64));
        vmax = fmaxf(vmax, __shfl_xor(vmax, 4, 64));
        vmax = fmaxf(vmax, __shfl_xor(vmax, 8, 64));
        vmax = fmaxf(vmax, __shfl_xor(vmax, 16, 64));
        vmax = fmaxf(vmax, __shfl_xor(vmax, 32, 64));
        if (!__all(vmax - m_run <= 8.0f)) {
            float nm = fmaxf(m_run, vmax);
            float fac = __expf(m_run - nm);
            m_run = nm;
            #pragma unroll
            for (int r = 0; r < 4; r++) lsum[r] *= fac;
            #pragma unroll
            for (int i = 0; i < 8; i++)
                #pragma unroll
                for (int r = 0; r < 4; r++) o[i][r] *= fac;
        }
        #pragma unroll
        for (int r = 0; r < 4; r++)
            #pragma unroll
            for (int nb = 0; nb < 4; nb++)
                pv_[r][nb] = __expf(pv_[r][nb] - m_run);

        // ---- P -> per-wave LDS, XOR-swizzled (write row=l4*4+r: byte ^= l4<<4) ----
        char* Pw = (char*)Ps[wave];
        #pragma unroll
        for (int r = 0; r < 4; r++) {
            int rowb = (l4*4 + r) * 144;
            #pragma unroll
            for (int nb = 0; nb < 4; nb++)
                *(short*)(Pw + rowb + (((nb*16 + lm)*2) ^ (l4 << 4))) =
                    (short)f2bf_rna(pv_[r][nb]);
        }

        // ---- PV + row-sum via ones-MFMA ----
        __builtin_amdgcn_s_setprio(1);
        #pragma unroll
        for (int ks = 0; ks < 2; ks++) {
            bf16x8 ap = *(const bf16x8*)(Pw + lm*144 +
                          ((ks*64 + l4*16) ^ ((lm & 12) << 2)));
            lsum = __builtin_amdgcn_mfma_f32_16x16x32_bf16(ap, onesb, lsum, 0, 0, 0);
            #pragma unroll
            for (int nd = 0; nd < 8; nd++) {
                int d = nd*16 + lm;
                bf16x8 bvv = *(const bf16x8*)(Vb +
                              (((d*128) + ks*64 + l4*16) ^ ((d & 7) << 4)));
                o[nd] = __builtin_amdgcn_mfma_f32_16x16x32_bf16(ap, bvv, o[nd], 0, 0, 0);
            }
        }
        __builtin_amdgcn_s_setprio(0);
        __builtin_amdgcn_s_barrier();
    }
    // drain wrapped prefetch before exit
    asm volatile("s_waitcnt vmcnt(0)" ::: "memory");
    __builtin_amdgcn_s_barrier();

    float inv[4];
    #pragma unroll
    for (int r = 0; r < 4; r++) inv[r] = 1.0f / lsum[r];
    #pragma unroll
    for (int nd = 0; nd < 8; nd++) {
        #pragma unroll
        for (int r = 0; r < 4; r++) {
            size_t row = (size_t)(zb*S_ + q0 + wave*16 + l4*4 + r);
            ctx[row * HD + h*DH_ + nd*16 + lm] = (short)f2bf(o[nd][r] * inv[r]);
        }
    }
}

extern "C" void kernel_launch(void* const* d_in, const int* in_sizes, int n_in,
                              void* d_out, int out_size, void* d_ws, size_t ws_size,
                              hipStream_t stream) {
    const float* x      = (const float*)d_in[0];
    const float* mask   = (const float*)d_in[1];
    const float* ln1_g  = (const float*)d_in[2];
    const float* ln1_b  = (const float*)d_in[3];
    const float* ln2_g  = (const float*)d_in[4];
    const float* ln2_b  = (const float*)d_in[5];
    const float* Wq     = (const float*)d_in[6];
    const float* Wk     = (const float*)d_in[7];
    const float* Wv     = (const float*)d_in[8];
    const float* Wo     = (const float*)d_in[9];
    const float* W1     = (const float*)d_in[10];
    const float* b1     = (const float*)d_in[11];
    const float* W2     = (const float*)d_in[12];
    const float* b2     = (const float*)d_in[13];
    float* out = (float*)d_out;

    char* ws = (char*)d_ws;
    size_t off = 0;
    const size_t WSQ  = (size_t)HD * HD * 2;        // 8 MiB
    const size_t WFF  = (size_t)HD * FF_ * 2;       // 32 MiB
    const size_t ACTB = (size_t)MROWS * HD * 2;     // 16 MiB
    short* WqkvT = (short*)(ws + off); off += 3 * WSQ;             // 24 MiB
    short* WoT   = (short*)(ws + off); off += WSQ;                 // 8
    short* W1T   = (short*)(ws + off); off += WFF;                 // 32
    short* W2T   = (short*)(ws + off); off += WFF;                 // 32
    short* hb    = (short*)(ws + off); off += ACTB;                // 16
    short* qkv   = (short*)(ws + off); off += (size_t)MROWS * LDQ * 2;  // 48
    short* vTb   = (short*)(ws + off); off += (size_t)HD * B_ * S_ * 2; // 16
    float* x1    = (float*)(ws + off); off += (size_t)MROWS * HD * 4;   // 32  (total 208 MiB)
    short* cb    = WqkvT;   // overlay: ctx over dead WqkvT
    short* act   = qkv;     // overlay: act (64 MiB) over dead qkv+vT

    dim3 blk(256);

    // weight convert+transpose (bf16, [N][K]); grid = (N/64, K/64)
    trcvt_kernel<<<dim3(HD/64,  HD/64),  blk, 0, stream>>>(Wq, WqkvT,                 HD, HD);
    trcvt_kernel<<<dim3(HD/64,  HD/64),  blk, 0, stream>>>(Wk, WqkvT + (size_t)HD*HD, HD, HD);
    trcvt_kernel<<<dim3(HD/64,  HD/64),  blk, 0, stream>>>(Wv, WqkvT + (size_t)2*HD*HD, HD, HD);
    trcvt_kernel<<<dim3(HD/64,  HD/64),  blk, 0, stream>>>(Wo, WoT, HD, HD);
    trcvt_kernel<<<dim3(FF_/64, HD/64),  blk, 0, stream>>>(W1, W1T, HD, FF_);
    trcvt_kernel<<<dim3(HD/64,  FF_/64), blk, 0, stream>>>(W2, W2T, FF_, HD);

    // 1) h = LN1(x) -> bf16
    ln_kernel<<<MROWS, blk, 0, stream>>>(x, ln1_g, ln1_b, hb);

    // 2) qkv = h @ [Wq|Wk|Wv]  (fused, N=6144); natural order (B L2-resident/XCD)
    gemm128<false,true,false,false,false><<<dim3((MROWS/128)*(LDQ/128)), 256, 0, stream>>>(
        hb, WqkvT, nullptr, nullptr, qkv, MROWS, LDQ, HD);

    // 2.5) vT[hd][b][s] = qkv v-part transposed
    vtrans_kernel<<<dim3(HD/32, S_/32, B_), blk, 0, stream>>>(qkv, vTb);

    // 3) ctx = softmax(qk^T*scale + mask) v  -> bf16 (over WqkvT)
    attn_kernel<<<dim3(S_/64, NH_, B_), blk, 0, stream>>>(qkv, vTb, mask, cb);

    // 4) x1 = x + ctx @ Wo  (f32); 32x16 grid -> XCD patch
    gemm128<true,false,false,true,false><<<dim3((MROWS/128)*(HD/128)), 256, 0, stream>>>(
        cb, WoT, nullptr, x, x1, MROWS, HD, HD);

    // 5) h2 = LN2(x1) -> bf16 (reuse hb)
    ln_kernel<<<MROWS, blk, 0, stream>>>(x1, ln2_g, ln2_b, hb);

    // 6) act = gelu(h2 @ W1 + b1) -> bf16; natural order
    gemm128<false,true,true,false,true><<<dim3((MROWS/128)*(FF_/128)), 256, 0, stream>>>(
        hb, W1T, b1, nullptr, act, MROWS, FF_, HD);

    // 7) out = x1 + act @ W2 + b2  (f32); 32x16 grid -> XCD patch
    gemm128<true,false,true,true,false><<<dim3((MROWS/128)*(HD/128)), 256, 0, stream>>>(
        act, W2T, b2, x1, out, MROWS, HD, FF_);
}

// Round 19
// 747.129 us; speedup vs baseline: 1.0924x; 1.0924x over previous
//
#include <hip/hip_runtime.h>
#include <math.h>

#define B_ 2
#define S_ 2048
#define HD 2048
#define NH_ 16
#define DH_ 128
#define FF_ 8192
#define MROWS (B_*S_)   // 4096
#define LDQ 6144        // fused qkv row stride

typedef __attribute__((ext_vector_type(8))) short bf16x8;
typedef __attribute__((ext_vector_type(4))) short s16x4;
typedef __attribute__((ext_vector_type(4))) float f32x4;

static __device__ __forceinline__ unsigned short f2bf(float f) {
    unsigned u = __float_as_uint(f);
    u += 0x7fffu + ((u >> 16) & 1u);   // round-to-nearest-even
    return (unsigned short)(u >> 16);
}

// RNA (round-half-away) — 2 ops; used only for P (>=0, differs from RNE at midpoints)
static __device__ __forceinline__ unsigned short f2bf_rna(float f) {
    return (unsigned short)((__float_as_uint(f) + 0x8000u) >> 16);
}

static __device__ __forceinline__ void gload_lds16(const void* g, void* lds) {
    __builtin_amdgcn_global_load_lds((const __attribute__((address_space(1))) void*)g,
                                     (__attribute__((address_space(3))) void*)lds, 16, 0, 0);
}

// ---------------- weight fp32 -> bf16 transpose: Wt[N][K] = bf16(W[K][N]) ----------------
__global__ __launch_bounds__(256) void trcvt_kernel(const float* __restrict__ W,
        short* __restrict__ Wt, int K, int N) {
    __shared__ float tile[64][65];
    int t = threadIdx.x;
    int tr = t >> 4;              // 0..15
    int tc4 = (t & 15) * 4;       // 0,4,..,60
    int r0 = blockIdx.y * 64, c0 = blockIdx.x * 64;   // r0: k, c0: n
    #pragma unroll
    for (int i = 0; i < 4; i++) {
        float4 v = *(const float4*)(W + (size_t)(r0 + tr + 16*i) * N + c0 + tc4);
        tile[tr + 16*i][tc4 + 0] = v.x;
        tile[tr + 16*i][tc4 + 1] = v.y;
        tile[tr + 16*i][tc4 + 2] = v.z;
        tile[tr + 16*i][tc4 + 3] = v.w;
    }
    __syncthreads();
    #pragma unroll
    for (int i = 0; i < 4; i++) {
        int oc = tr + 16*i;       // n_local
        s16x4 o;
        o.x = (short)f2bf(tile[tc4 + 0][oc]);
        o.y = (short)f2bf(tile[tc4 + 1][oc]);
        o.z = (short)f2bf(tile[tc4 + 2][oc]);
        o.w = (short)f2bf(tile[tc4 + 3][oc]);
        *(s16x4*)(Wt + (size_t)(c0 + oc) * K + r0 + tc4) = o;
    }
}

// ---------------- V transpose: vT[(hd)*2 + b][s] = qkv[b*S+s][4096+hd] ----------------
__global__ __launch_bounds__(256) void vtrans_kernel(const short* __restrict__ qkv,
        short* __restrict__ vT) {
    __shared__ short tile[32][33];
    int t = threadIdx.x;
    int tx = t & 31, ty = t >> 5;
    int c0 = blockIdx.x * 32;          // hd
    int r0 = blockIdx.y * 32;          // s
    int b  = blockIdx.z;
    #pragma unroll
    for (int i = 0; i < 4; i++)
        tile[ty + 8*i][tx] = qkv[(size_t)(b*S_ + r0 + ty + 8*i) * LDQ + 4096 + c0 + tx];
    __syncthreads();
    #pragma unroll
    for (int i = 0; i < 4; i++)
        vT[((size_t)(c0 + ty + 8*i) * 2 + b) * S_ + r0 + tx] = tile[tx][ty + 8*i];
}

// ---------------- LayerNorm fp32 in -> bf16 out ----------------
__global__ __launch_bounds__(256) void ln_kernel(const float* __restrict__ x,
                const float* __restrict__ g, const float* __restrict__ b,
                short* __restrict__ out) {
    int row = blockIdx.x;
    const float* xr = x + (size_t)row * HD;
    short* orow = out + (size_t)row * HD;
    int t = threadIdx.x;

    float4 v0 = ((const float4*)xr)[t];
    float4 v1 = ((const float4*)xr)[t + 256];
    float s  = v0.x + v0.y + v0.z + v0.w + v1.x + v1.y + v1.z + v1.w;
    float ss = v0.x*v0.x + v0.y*v0.y + v0.z*v0.z + v0.w*v0.w
             + v1.x*v1.x + v1.y*v1.y + v1.z*v1.z + v1.w*v1.w;

    #pragma unroll
    for (int off = 1; off < 64; off <<= 1) {
        s  += __shfl_xor(s,  off, 64);
        ss += __shfl_xor(ss, off, 64);
    }
    __shared__ float ws_s[4], ws_q[4];
    int wid = t >> 6;
    if ((t & 63) == 0) { ws_s[wid] = s; ws_q[wid] = ss; }
    __syncthreads();
    s  = ws_s[0] + ws_s[1] + ws_s[2] + ws_s[3];
    ss = ws_q[0] + ws_q[1] + ws_q[2] + ws_q[3];

    float mu  = s * (1.0f / HD);
    float var = ss * (1.0f / HD) - mu * mu;
    float rs  = rsqrtf(var + 1e-5f);

    float4 g0 = ((const float4*)g)[t];
    float4 g1 = ((const float4*)g)[t + 256];
    float4 b0 = ((const float4*)b)[t];
    float4 b1 = ((const float4*)b)[t + 256];
    s16x4 o0, o1;
    o0.x = (short)f2bf((v0.x - mu) * rs * g0.x + b0.x);
    o0.y = (short)f2bf((v0.y - mu) * rs * g0.y + b0.y);
    o0.z = (short)f2bf((v0.z - mu) * rs * g0.z + b0.z);
    o0.w = (short)f2bf((v0.w - mu) * rs * g0.w + b0.w);
    o1.x = (short)f2bf((v1.x - mu) * rs * g1.x + b1.x);
    o1.y = (short)f2bf((v1.y - mu) * rs * g1.y + b1.y);
    o1.z = (short)f2bf((v1.z - mu) * rs * g1.z + b1.z);
    o1.w = (short)f2bf((v1.w - mu) * rs * g1.w + b1.w);
    ((s16x4*)orow)[t]       = o0;
    ((s16x4*)orow)[t + 256] = o1;
}

// =================== 128x128 ring-2 MFMA GEMM (64 KiB LDS -> 2 blocks/CU) ===================
// C = epi(A[M][K] @ Bt[N][K]^T). 256 thr = 4 waves (2x2), per-wave out 64x64.
// Per iter: stage T+1 into other buffer (WAR-safe), vmcnt(8) retires exactly tile
// t's loads, barrier, 16 ds_read_b128 + 32 MFMA, barrier. Swizzle chunk^=(row&7):
// bank-conflict-free (measured 0 @ r12/r17). BK=32 variant regressed (r18) — keep BK=64.
template<bool PATCH, bool OUTBF16, bool BIAS, bool RES, bool GELU>
__global__ __launch_bounds__(256, 2) void gemm128(
        const short* __restrict__ A, const short* __restrict__ Bt,
        const float* __restrict__ bias, const float* __restrict__ res,
        void* __restrict__ Cout, int M, int N, int K) {
    __shared__ __align__(16) char ldsA[2][128 * 128];   // 16 KB per buf
    __shared__ __align__(16) char ldsB[2][128 * 128];

    int tid = threadIdx.x;
    int wave = tid >> 6, lane = tid & 63;
    int l4 = lane >> 4, lm = lane & 15;
    int wm = wave >> 1, wn = wave & 1;

    int bid = blockIdx.x;
    int m0, n0;
    if constexpr (PATCH) {
        // grid must be 32 m-tiles x 16 n-tiles (M=4096, N=2048)
        int xcd = bid & 7, local = bid >> 3;
        m0 = ((xcd & 3) * 8 + (local & 7)) << 7;
        n0 = ((xcd >> 2) * 8 + (local >> 3)) << 7;
    } else {
        int nx = N >> 7;
        m0 = (bid / nx) << 7; n0 = (bid % nx) << 7;
    }

    const short* Atile = A + (size_t)m0 * K;
    const short* Btile = Bt + (size_t)n0 * K;
    const int NT = K >> 6;

    auto stage = [&](int t, int buf) {
        int tw = (t >= NT) ? t - NT : t;
        const short* gA = Atile + tw * 64;
        const short* gB = Btile + tw * 64;
        #pragma unroll
        for (int s = 0; s < 4; s++) {
            int n = (wave * 4 + s) * 64 + lane;
            int row = n >> 3, c = n & 7;
            int cs = c ^ (row & 7);
            gload_lds16(gA + (size_t)row * K + cs * 8, ldsA[buf] + n * 16);
            gload_lds16(gB + (size_t)row * K + cs * 8, ldsB[buf] + n * 16);
        }
    };

    int ch0 = (l4) ^ (lm & 7);
    int ch1 = (4 | l4) ^ (lm & 7);
    const char* pA = (const char*)ldsA + (wm * 64 + lm) * 128;
    const char* pB = (const char*)ldsB + (wn * 64 + lm) * 128;

    f32x4 acc[4][4] = {};

    stage(0, 0);
    for (int t = 0; t < NT; t++) {
        int buf = t & 1;
        stage(t + 1, buf ^ 1);
        asm volatile("s_waitcnt vmcnt(8)" ::: "memory");
        __builtin_amdgcn_s_barrier();
        __builtin_amdgcn_sched_barrier(0);
        size_t bo = (size_t)buf * 128 * 128;
        __builtin_amdgcn_s_setprio(1);
        #pragma unroll
        for (int kk = 0; kk < 2; kk++) {
            int ch = kk ? ch1 : ch0;
            bf16x8 av[4], bv[4];
            #pragma unroll
            for (int f = 0; f < 4; f++)
                av[f] = *(const bf16x8*)(pA + bo + f * 2048 + ch * 16);
            #pragma unroll
            for (int nn = 0; nn < 4; nn++)
                bv[nn] = *(const bf16x8*)(pB + bo + nn * 2048 + ch * 16);
            #pragma unroll
            for (int f = 0; f < 4; f++)
                #pragma unroll
                for (int nn = 0; nn < 4; nn++)
                    acc[f][nn] = __builtin_amdgcn_mfma_f32_16x16x32_bf16(
                        av[f], bv[nn], acc[f][nn], 0, 0, 0);
        }
        __builtin_amdgcn_s_setprio(0);
        __builtin_amdgcn_s_barrier();
    }
    asm volatile("s_waitcnt vmcnt(0)" ::: "memory");
    __builtin_amdgcn_s_barrier();

    #pragma unroll
    for (int nn = 0; nn < 4; nn++) {
        int colb = n0 + wn * 64 + nn * 16 + lm;
        float bvs = BIAS ? bias[colb] : 0.f;
        #pragma unroll
        for (int m = 0; m < 4; m++) {
            #pragma unroll
            for (int r = 0; r < 4; r++) {
                int row = m0 + wm * 64 + m * 16 + l4 * 4 + r;
                float v = acc[m][nn][r] + bvs;
                if (GELU) {
                    // tanh-form GELU as sigmoid: v*sigma(1.5957691(v+0.044715 v^3))
                    float y = 1.5957691f * (v + 0.044715f * v * v * v);
                    v = v / (1.0f + __expf(-y));
                }
                size_t off = (size_t)row * N + colb;
                if (RES) v += res[off];
                if (OUTBF16) ((short*)Cout)[off] = (short)f2bf(v);
                else         ((float*)Cout)[off] = v;
            }
        }
    }
}

// ---------------- MFMA flash attention (tile-max + MFMA row-sum + swizzled P) ----------------
__global__ __launch_bounds__(256) void attn_kernel(
        const short* __restrict__ qkv, const short* __restrict__ vT,
        const float* __restrict__ mask, short* __restrict__ ctx) {
    __shared__ __align__(16) short Ks[2][64*128];   // [kv][d], chunk-swizzled
    __shared__ __align__(16) short Vt[2][128*64];   // [d][kv], chunk-swizzled
    __shared__ __align__(16) short Ps[4][16*72];    // per-wave P, pitch 72, XOR-swizzled
    int t = threadIdx.x;
    int wave = t >> 6, lane = t & 63;
    int l4 = lane >> 4, lm = lane & 15;
    int q0 = blockIdx.x * 64, h = blockIdx.y, zb = blockIdx.z;
    const float scale = 0.08838834764831845f;  // 1/sqrt(128)
    const int NT = S_ / 64;                    // 32 tiles

    bf16x8 aq[4];
    {
        const short* qrow = qkv + (size_t)(zb*S_ + q0 + wave*16 + lm) * LDQ + h*DH_;
        #pragma unroll
        for (int ks = 0; ks < 4; ks++)
            aq[ks] = *(const bf16x8*)(qrow + ks*32 + l4*8);
    }
    bf16x8 onesb;
    #pragma unroll
    for (int i = 0; i < 8; i++) onesb[i] = (short)0x3F80;   // bf16 1.0

    auto stageKV = [&](int ti, int buf) {
        int tw = (ti >= NT) ? ti - NT : ti;
        int kv0 = tw * 64;
        #pragma unroll
        for (int L = 0; L < 4; L++) {
            int c = (wave*4 + L)*64 + lane;
            int krow = c >> 4, kc = c & 15;
            int ksrc = (kc & 8) | ((kc ^ (krow & 7)) & 7);
            gload_lds16(qkv + (size_t)(zb*S_ + kv0 + krow)*LDQ + 2048 + h*DH_ + ksrc*8,
                        (char*)Ks[buf] + c*16);
            int drow = c >> 3, dc = c & 7;
            int dsrc = dc ^ (drow & 7);
            gload_lds16(vT + ((size_t)(h*DH_ + drow)*2 + zb)*S_ + kv0 + dsrc*8,
                        (char*)Vt[buf] + c*16);
        }
    };

    float m_run = -INFINITY;
    f32x4 lsum = (f32x4){0.f, 0.f, 0.f, 0.f};
    f32x4 o[8];
    #pragma unroll
    for (int i = 0; i < 8; i++) o[i] = (f32x4){0.f, 0.f, 0.f, 0.f};

    stageKV(0, 0);
    for (int ti = 0; ti < NT; ti++) {
        int buf = ti & 1;
        int kv0 = ti * 64;
        stageKV(ti + 1, buf ^ 1);
        asm volatile("s_waitcnt vmcnt(8)" ::: "memory");
        __builtin_amdgcn_s_barrier();
        __builtin_amdgcn_sched_barrier(0);
        const char* Kb = (const char*)Ks[buf];
        const char* Vb = (const char*)Vt[buf];

        f32x4 s[4];
        #pragma unroll
        for (int nb = 0; nb < 4; nb++) s[nb] = (f32x4){0.f, 0.f, 0.f, 0.f};
        __builtin_amdgcn_s_setprio(1);
        #pragma unroll
        for (int nb = 0; nb < 4; nb++) {
            int row = nb*16 + lm;
            #pragma unroll
            for (int ks = 0; ks < 4; ks++) {
                bf16x8 bk = *(const bf16x8*)(Kb +
                              ((row*256 + ks*64 + l4*16) ^ ((row & 7) << 4)));
                s[nb] = __builtin_amdgcn_mfma_f32_16x16x32_bf16(aq[ks], bk, s[nb], 0, 0, 0);
            }
        }
        __builtin_amdgcn_s_setprio(0);

        float mk[4];
        #pragma unroll
        for (int nb = 0; nb < 4; nb++) mk[nb] = mask[(size_t)zb*S_ + kv0 + nb*16 + lm];

        // ---- tile-wide max + defer (wave-uniform m) ----
        float pv_[4][4];
        float vmax = -INFINITY;
        #pragma unroll
        for (int r = 0; r < 4; r++)
            #pragma unroll
            for (int nb = 0; nb < 4; nb++) {
                float v = fmaf(s[nb][r], scale, mk[nb]);
                pv_[r][nb] = v;
                vmax = fmaxf(vmax, v);
            }
        vmax = fmaxf(vmax, __shfl_xor(vmax, 1, 64));
        vmax = fmaxf(vmax, __shfl_xor(vmax, 2, 64));
        vmax = fmaxf(vmax, __shfl_xor(vmax, 4, 64));
        vmax = fmaxf(vmax, __shfl_xor(vmax, 8, 64));
        vmax = fmaxf(vmax, __shfl_xor(vmax, 16, 64));
        vmax = fmaxf(vmax, __shfl_xor(vmax, 32, 64));
        if (!__all(vmax - m_run <= 8.0f)) {
            float nm = fmaxf(m_run, vmax);
            float fac = __expf(m_run - nm);
            m_run = nm;
            #pragma unroll
            for (int r = 0; r < 4; r++) lsum[r] *= fac;
            #pragma unroll
            for (int i = 0; i < 8; i++)
                #pragma unroll
                for (int r = 0; r < 4; r++) o[i][r] *= fac;
        }
        #pragma unroll
        for (int r = 0; r < 4; r++)
            #pragma unroll
            for (int nb = 0; nb < 4; nb++)
                pv_[r][nb] = __expf(pv_[r][nb] - m_run);

        // ---- P -> per-wave LDS, XOR-swizzled (write row=l4*4+r: byte ^= l4<<4) ----
        char* Pw = (char*)Ps[wave];
        #pragma unroll
        for (int r = 0; r < 4; r++) {
            int rowb = (l4*4 + r) * 144;
            #pragma unroll
            for (int nb = 0; nb < 4; nb++)
                *(short*)(Pw + rowb + (((nb*16 + lm)*2) ^ (l4 << 4))) =
                    (short)f2bf_rna(pv_[r][nb]);
        }

        // ---- PV + row-sum via ones-MFMA ----
        __builtin_amdgcn_s_setprio(1);
        #pragma unroll
        for (int ks = 0; ks < 2; ks++) {
            bf16x8 ap = *(const bf16x8*)(Pw + lm*144 +
                          ((ks*64 + l4*16) ^ ((lm & 12) << 2)));
            lsum = __builtin_amdgcn_mfma_f32_16x16x32_bf16(ap, onesb, lsum, 0, 0, 0);
            #pragma unroll
            for (int nd = 0; nd < 8; nd++) {
                int d = nd*16 + lm;
                bf16x8 bvv = *(const bf16x8*)(Vb +
                              (((d*128) + ks*64 + l4*16) ^ ((d & 7) << 4)));
                o[nd] = __builtin_amdgcn_mfma_f32_16x16x32_bf16(ap, bvv, o[nd], 0, 0, 0);
            }
        }
        __builtin_amdgcn_s_setprio(0);
        __builtin_amdgcn_s_barrier();
    }
    // drain wrapped prefetch before exit
    asm volatile("s_waitcnt vmcnt(0)" ::: "memory");
    __builtin_amdgcn_s_barrier();

    float inv[4];
    #pragma unroll
    for (int r = 0; r < 4; r++) inv[r] = 1.0f / lsum[r];
    #pragma unroll
    for (int nd = 0; nd < 8; nd++) {
        #pragma unroll
        for (int r = 0; r < 4; r++) {
            size_t row = (size_t)(zb*S_ + q0 + wave*16 + l4*4 + r);
            ctx[row * HD + h*DH_ + nd*16 + lm] = (short)f2bf(o[nd][r] * inv[r]);
        }
    }
}

extern "C" void kernel_launch(void* const* d_in, const int* in_sizes, int n_in,
                              void* d_out, int out_size, void* d_ws, size_t ws_size,
                              hipStream_t stream) {
    const float* x      = (const float*)d_in[0];
    const float* mask   = (const float*)d_in[1];
    const float* ln1_g  = (const float*)d_in[2];
    const float* ln1_b  = (const float*)d_in[3];
    const float* ln2_g  = (const float*)d_in[4];
    const float* ln2_b  = (const float*)d_in[5];
    const float* Wq     = (const float*)d_in[6];
    const float* Wk     = (const float*)d_in[7];
    const float* Wv     = (const float*)d_in[8];
    const float* Wo     = (const float*)d_in[9];
    const float* W1     = (const float*)d_in[10];
    const float* b1     = (const float*)d_in[11];
    const float* W2     = (const float*)d_in[12];
    const float* b2     = (const float*)d_in[13];
    float* out = (float*)d_out;

    char* ws = (char*)d_ws;
    size_t off = 0;
    const size_t WSQ  = (size_t)HD * HD * 2;        // 8 MiB
    const size_t WFF  = (size_t)HD * FF_ * 2;       // 32 MiB
    const size_t ACTB = (size_t)MROWS * HD * 2;     // 16 MiB
    short* WqkvT = (short*)(ws + off); off += 3 * WSQ;             // 24 MiB
    short* WoT   = (short*)(ws + off); off += WSQ;                 // 8
    short* W1T   = (short*)(ws + off); off += WFF;                 // 32
    short* W2T   = (short*)(ws + off); off += WFF;                 // 32
    short* hb    = (short*)(ws + off); off += ACTB;                // 16
    short* qkv   = (short*)(ws + off); off += (size_t)MROWS * LDQ * 2;  // 48
    short* vTb   = (short*)(ws + off); off += (size_t)HD * B_ * S_ * 2; // 16
    float* x1    = (float*)(ws + off); off += (size_t)MROWS * HD * 4;   // 32  (total 208 MiB)
    short* cb    = WqkvT;   // overlay: ctx over dead WqkvT
    short* act   = qkv;     // overlay: act (64 MiB) over dead qkv+vT

    dim3 blk(256);

    // weight convert+transpose (bf16, [N][K]); grid = (N/64, K/64)
    trcvt_kernel<<<dim3(HD/64,  HD/64),  blk, 0, stream>>>(Wq, WqkvT,                 HD, HD);
    trcvt_kernel<<<dim3(HD/64,  HD/64),  blk, 0, stream>>>(Wk, WqkvT + (size_t)HD*HD, HD, HD);
    trcvt_kernel<<<dim3(HD/64,  HD/64),  blk, 0, stream>>>(Wv, WqkvT + (size_t)2*HD*HD, HD, HD);
    trcvt_kernel<<<dim3(HD/64,  HD/64),  blk, 0, stream>>>(Wo, WoT, HD, HD);
    trcvt_kernel<<<dim3(FF_/64, HD/64),  blk, 0, stream>>>(W1, W1T, HD, FF_);
    trcvt_kernel<<<dim3(HD/64,  FF_/64), blk, 0, stream>>>(W2, W2T, FF_, HD);

    // 1) h = LN1(x) -> bf16
    ln_kernel<<<MROWS, blk, 0, stream>>>(x, ln1_g, ln1_b, hb);

    // 2) qkv = h @ [Wq|Wk|Wv]  (fused, N=6144); natural order (B L2-resident/XCD)
    gemm128<false,true,false,false,false><<<dim3((MROWS/128)*(LDQ/128)), 256, 0, stream>>>(
        hb, WqkvT, nullptr, nullptr, qkv, MROWS, LDQ, HD);

    // 2.5) vT[hd][b][s] = qkv v-part transposed
    vtrans_kernel<<<dim3(HD/32, S_/32, B_), blk, 0, stream>>>(qkv, vTb);

    // 3) ctx = softmax(qk^T*scale + mask) v  -> bf16 (over WqkvT)
    attn_kernel<<<dim3(S_/64, NH_, B_), blk, 0, stream>>>(qkv, vTb, mask, cb);

    // 4) x1 = x + ctx @ Wo  (f32); 32x16 grid -> XCD patch
    gemm128<true,false,false,true,false><<<dim3((MROWS/128)*(HD/128)), 256, 0, stream>>>(
        cb, WoT, nullptr, x, x1, MROWS, HD, HD);

    // 5) h2 = LN2(x1) -> bf16 (reuse hb)
    ln_kernel<<<MROWS, blk, 0, stream>>>(x1, ln2_g, ln2_b, hb);

    // 6) act = gelu(h2 @ W1 + b1) -> bf16; natural order
    gemm128<false,true,true,false,true><<<dim3((MROWS/128)*(FF_/128)), 256, 0, stream>>>(
        hb, W1T, b1, nullptr, act, MROWS, FF_, HD);

    // 7) out = x1 + act @ W2 + b2  (f32); 32x16 grid -> XCD patch
    gemm128<true,false,true,true,false><<<dim3((MROWS/128)*(HD/128)), 256, 0, stream>>>(
        act, W2T, b2, x1, out, MROWS, HD, FF_);
}

// Round 20
// 707.946 us; speedup vs baseline: 1.1528x; 1.0553x over previous
//
#include <hip/hip_runtime.h>
#include <math.h>

#define B_ 2
#define S_ 2048
#define HD 2048
#define NH_ 16
#define DH_ 128
#define FF_ 8192
#define MROWS (B_*S_)   // 4096
#define LDQ 6144        // fused qkv row stride

typedef __attribute__((ext_vector_type(8))) short bf16x8;
typedef __attribute__((ext_vector_type(4))) short s16x4;
typedef __attribute__((ext_vector_type(4))) float f32x4;

static __device__ __forceinline__ unsigned short f2bf(float f) {
    unsigned u = __float_as_uint(f);
    u += 0x7fffu + ((u >> 16) & 1u);   // round-to-nearest-even
    return (unsigned short)(u >> 16);
}

// RNA (round-half-away) — 2 ops; used only for P (>=0, differs from RNE at midpoints)
static __device__ __forceinline__ unsigned short f2bf_rna(float f) {
    return (unsigned short)((__float_as_uint(f) + 0x8000u) >> 16);
}

static __device__ __forceinline__ float bf2f(unsigned short s) {
    return __uint_as_float((unsigned)s << 16);
}

static __device__ __forceinline__ void gload_lds16(const void* g, void* lds) {
    __builtin_amdgcn_global_load_lds((const __attribute__((address_space(1))) void*)g,
                                     (__attribute__((address_space(3))) void*)lds, 16, 0, 0);
}

// ---------------- weight fp32 -> bf16 transpose: Wt[N][K] = bf16(W[K][N]) ----------------
__global__ __launch_bounds__(256) void trcvt_kernel(const float* __restrict__ W,
        short* __restrict__ Wt, int K, int N) {
    __shared__ float tile[64][65];
    int t = threadIdx.x;
    int tr = t >> 4;              // 0..15
    int tc4 = (t & 15) * 4;       // 0,4,..,60
    int r0 = blockIdx.y * 64, c0 = blockIdx.x * 64;   // r0: k, c0: n
    #pragma unroll
    for (int i = 0; i < 4; i++) {
        float4 v = *(const float4*)(W + (size_t)(r0 + tr + 16*i) * N + c0 + tc4);
        tile[tr + 16*i][tc4 + 0] = v.x;
        tile[tr + 16*i][tc4 + 1] = v.y;
        tile[tr + 16*i][tc4 + 2] = v.z;
        tile[tr + 16*i][tc4 + 3] = v.w;
    }
    __syncthreads();
    #pragma unroll
    for (int i = 0; i < 4; i++) {
        int oc = tr + 16*i;       // n_local
        s16x4 o;
        o.x = (short)f2bf(tile[tc4 + 0][oc]);
        o.y = (short)f2bf(tile[tc4 + 1][oc]);
        o.z = (short)f2bf(tile[tc4 + 2][oc]);
        o.w = (short)f2bf(tile[tc4 + 3][oc]);
        *(s16x4*)(Wt + (size_t)(c0 + oc) * K + r0 + tc4) = o;
    }
}

// merged square (HD x HD) transposes: z=0..2 -> WqkvT slabs, z=3 -> WoT
__global__ __launch_bounds__(256) void trcvt4_kernel(
        const float* __restrict__ w0, const float* __restrict__ w1,
        const float* __restrict__ w2, const float* __restrict__ w3,
        short* __restrict__ dqkv, short* __restrict__ dwo) {
    __shared__ float tile[64][65];
    int z = blockIdx.z;
    const float* W = (z == 0) ? w0 : (z == 1) ? w1 : (z == 2) ? w2 : w3;
    short* Wt = (z < 3) ? (dqkv + (size_t)z * HD * HD) : dwo;
    int t = threadIdx.x;
    int tr = t >> 4, tc4 = (t & 15) * 4;
    int r0 = blockIdx.y * 64, c0 = blockIdx.x * 64;
    #pragma unroll
    for (int i = 0; i < 4; i++) {
        float4 v = *(const float4*)(W + (size_t)(r0 + tr + 16*i) * HD + c0 + tc4);
        tile[tr + 16*i][tc4 + 0] = v.x;
        tile[tr + 16*i][tc4 + 1] = v.y;
        tile[tr + 16*i][tc4 + 2] = v.z;
        tile[tr + 16*i][tc4 + 3] = v.w;
    }
    __syncthreads();
    #pragma unroll
    for (int i = 0; i < 4; i++) {
        int oc = tr + 16*i;
        s16x4 o;
        o.x = (short)f2bf(tile[tc4 + 0][oc]);
        o.y = (short)f2bf(tile[tc4 + 1][oc]);
        o.z = (short)f2bf(tile[tc4 + 2][oc]);
        o.w = (short)f2bf(tile[tc4 + 3][oc]);
        *(s16x4*)(Wt + (size_t)(c0 + oc) * HD + r0 + tc4) = o;
    }
}

// ---------------- V transpose: vT[(hd)*2 + b][s] = qkv[b*S+s][4096+hd] ----------------
__global__ __launch_bounds__(256) void vtrans_kernel(const short* __restrict__ qkv,
        short* __restrict__ vT) {
    __shared__ short tile[32][33];
    int t = threadIdx.x;
    int tx = t & 31, ty = t >> 5;
    int c0 = blockIdx.x * 32;          // hd
    int r0 = blockIdx.y * 32;          // s
    int b  = blockIdx.z;
    #pragma unroll
    for (int i = 0; i < 4; i++)
        tile[ty + 8*i][tx] = qkv[(size_t)(b*S_ + r0 + ty + 8*i) * LDQ + 4096 + c0 + tx];
    __syncthreads();
    #pragma unroll
    for (int i = 0; i < 4; i++)
        vT[((size_t)(c0 + ty + 8*i) * 2 + b) * S_ + r0 + tx] = tile[tx][ty + 8*i];
}

// ---------------- LayerNorm (f32 or bf16 input) -> bf16 out ----------------
template<bool INBF16>
__global__ __launch_bounds__(256) void ln_kernel(const void* __restrict__ xin,
                const float* __restrict__ g, const float* __restrict__ b,
                short* __restrict__ out) {
    int row = blockIdx.x;
    int t = threadIdx.x;
    short* orow = out + (size_t)row * HD;

    float a[8];
    if (INBF16) {
        const short* xr = (const short*)xin + (size_t)row * HD;
        bf16x8 v = ((const bf16x8*)xr)[t];
        #pragma unroll
        for (int i = 0; i < 8; i++) a[i] = bf2f((unsigned short)v[i]);
    } else {
        const float* xr = (const float*)xin + (size_t)row * HD;
        float4 v0 = ((const float4*)xr)[2*t];
        float4 v1 = ((const float4*)xr)[2*t + 1];
        a[0]=v0.x; a[1]=v0.y; a[2]=v0.z; a[3]=v0.w;
        a[4]=v1.x; a[5]=v1.y; a[6]=v1.z; a[7]=v1.w;
    }
    float s = 0.f, ss = 0.f;
    #pragma unroll
    for (int i = 0; i < 8; i++) { s += a[i]; ss += a[i]*a[i]; }

    #pragma unroll
    for (int off = 1; off < 64; off <<= 1) {
        s  += __shfl_xor(s,  off, 64);
        ss += __shfl_xor(ss, off, 64);
    }
    __shared__ float ws_s[4], ws_q[4];
    int wid = t >> 6;
    if ((t & 63) == 0) { ws_s[wid] = s; ws_q[wid] = ss; }
    __syncthreads();
    s  = ws_s[0] + ws_s[1] + ws_s[2] + ws_s[3];
    ss = ws_q[0] + ws_q[1] + ws_q[2] + ws_q[3];

    float mu  = s * (1.0f / HD);
    float var = ss * (1.0f / HD) - mu * mu;
    float rs  = rsqrtf(var + 1e-5f);

    float4 g0 = ((const float4*)g)[2*t];
    float4 g1 = ((const float4*)g)[2*t + 1];
    float4 b0 = ((const float4*)b)[2*t];
    float4 b1 = ((const float4*)b)[2*t + 1];
    float gg[8] = {g0.x,g0.y,g0.z,g0.w,g1.x,g1.y,g1.z,g1.w};
    float bb[8] = {b0.x,b0.y,b0.z,b0.w,b1.x,b1.y,b1.z,b1.w};
    bf16x8 o;
    #pragma unroll
    for (int i = 0; i < 8; i++)
        o[i] = (short)f2bf((a[i] - mu) * rs * gg[i] + bb[i]);
    *(bf16x8*)(orow + 8*t) = o;
}

// =================== 128x128 ring-2 MFMA GEMM (64 KiB LDS -> 2 blocks/CU) ===================
// C = epi(A[M][K] @ Bt[N][K]^T). 256 thr = 4 waves (2x2), per-wave out 64x64.
// Per iter: stage T+1 into other buffer (WAR-safe), vmcnt(8) retires exactly tile
// t's loads, barrier, 16 ds_read_b128 + 32 MFMA, barrier. Swizzle chunk^=(row&7):
// bank-conflict-free (measured 0 @ r12/r17). BK=32 variant regressed (r18) — keep BK=64.
template<bool PATCH, bool OUTBF16, bool BIAS, bool RES, bool RESBF16, bool GELU>
__global__ __launch_bounds__(256, 2) void gemm128(
        const short* __restrict__ A, const short* __restrict__ Bt,
        const float* __restrict__ bias, const void* __restrict__ res,
        void* __restrict__ Cout, int M, int N, int K) {
    __shared__ __align__(16) char ldsA[2][128 * 128];   // 16 KB per buf
    __shared__ __align__(16) char ldsB[2][128 * 128];

    int tid = threadIdx.x;
    int wave = tid >> 6, lane = tid & 63;
    int l4 = lane >> 4, lm = lane & 15;
    int wm = wave >> 1, wn = wave & 1;

    int bid = blockIdx.x;
    int m0, n0;
    if constexpr (PATCH) {
        // grid must be 32 m-tiles x 16 n-tiles (M=4096, N=2048)
        int xcd = bid & 7, local = bid >> 3;
        m0 = ((xcd & 3) * 8 + (local & 7)) << 7;
        n0 = ((xcd >> 2) * 8 + (local >> 3)) << 7;
    } else {
        int nx = N >> 7;
        m0 = (bid / nx) << 7; n0 = (bid % nx) << 7;
    }

    const short* Atile = A + (size_t)m0 * K;
    const short* Btile = Bt + (size_t)n0 * K;
    const int NT = K >> 6;

    auto stage = [&](int t, int buf) {
        int tw = (t >= NT) ? t - NT : t;
        const short* gA = Atile + tw * 64;
        const short* gB = Btile + tw * 64;
        #pragma unroll
        for (int s = 0; s < 4; s++) {
            int n = (wave * 4 + s) * 64 + lane;
            int row = n >> 3, c = n & 7;
            int cs = c ^ (row & 7);
            gload_lds16(gA + (size_t)row * K + cs * 8, ldsA[buf] + n * 16);
            gload_lds16(gB + (size_t)row * K + cs * 8, ldsB[buf] + n * 16);
        }
    };

    int ch0 = (l4) ^ (lm & 7);
    int ch1 = (4 | l4) ^ (lm & 7);
    const char* pA = (const char*)ldsA + (wm * 64 + lm) * 128;
    const char* pB = (const char*)ldsB + (wn * 64 + lm) * 128;

    f32x4 acc[4][4] = {};

    stage(0, 0);
    for (int t = 0; t < NT; t++) {
        int buf = t & 1;
        stage(t + 1, buf ^ 1);
        asm volatile("s_waitcnt vmcnt(8)" ::: "memory");
        __builtin_amdgcn_s_barrier();
        __builtin_amdgcn_sched_barrier(0);
        size_t bo = (size_t)buf * 128 * 128;
        __builtin_amdgcn_s_setprio(1);
        #pragma unroll
        for (int kk = 0; kk < 2; kk++) {
            int ch = kk ? ch1 : ch0;
            bf16x8 av[4], bv[4];
            #pragma unroll
            for (int f = 0; f < 4; f++)
                av[f] = *(const bf16x8*)(pA + bo + f * 2048 + ch * 16);
            #pragma unroll
            for (int nn = 0; nn < 4; nn++)
                bv[nn] = *(const bf16x8*)(pB + bo + nn * 2048 + ch * 16);
            #pragma unroll
            for (int f = 0; f < 4; f++)
                #pragma unroll
                for (int nn = 0; nn < 4; nn++)
                    acc[f][nn] = __builtin_amdgcn_mfma_f32_16x16x32_bf16(
                        av[f], bv[nn], acc[f][nn], 0, 0, 0);
        }
        __builtin_amdgcn_s_setprio(0);
        __builtin_amdgcn_s_barrier();
    }
    asm volatile("s_waitcnt vmcnt(0)" ::: "memory");
    __builtin_amdgcn_s_barrier();

    #pragma unroll
    for (int nn = 0; nn < 4; nn++) {
        int colb = n0 + wn * 64 + nn * 16 + lm;
        float bvs = BIAS ? bias[colb] : 0.f;
        #pragma unroll
        for (int m = 0; m < 4; m++) {
            #pragma unroll
            for (int r = 0; r < 4; r++) {
                int row = m0 + wm * 64 + m * 16 + l4 * 4 + r;
                float v = acc[m][nn][r] + bvs;
                if (GELU) {
                    // tanh-form GELU as sigmoid: v*sigma(1.5957691(v+0.044715 v^3))
                    float y = 1.5957691f * (v + 0.044715f * v * v * v);
                    v = v / (1.0f + __expf(-y));
                }
                size_t off = (size_t)row * N + colb;
                if (RES) {
                    if (RESBF16) v += bf2f(((const unsigned short*)res)[off]);
                    else         v += ((const float*)res)[off];
                }
                if (OUTBF16) ((short*)Cout)[off] = (short)f2bf(v);
                else         ((float*)Cout)[off] = v;
            }
        }
    }
}

// ---------------- MFMA flash attention (tile-max + MFMA row-sum + swizzled P) ----------------
__global__ __launch_bounds__(256) void attn_kernel(
        const short* __restrict__ qkv, const short* __restrict__ vT,
        const float* __restrict__ mask, short* __restrict__ ctx) {
    __shared__ __align__(16) short Ks[2][64*128];   // [kv][d], chunk-swizzled
    __shared__ __align__(16) short Vt[2][128*64];   // [d][kv], chunk-swizzled
    __shared__ __align__(16) short Ps[4][16*72];    // per-wave P, pitch 72, XOR-swizzled
    int t = threadIdx.x;
    int wave = t >> 6, lane = t & 63;
    int l4 = lane >> 4, lm = lane & 15;
    int q0 = blockIdx.x * 64, h = blockIdx.y, zb = blockIdx.z;
    const float scale = 0.08838834764831845f;  // 1/sqrt(128)
    const int NT = S_ / 64;                    // 32 tiles

    bf16x8 aq[4];
    {
        const short* qrow = qkv + (size_t)(zb*S_ + q0 + wave*16 + lm) * LDQ + h*DH_;
        #pragma unroll
        for (int ks = 0; ks < 4; ks++)
            aq[ks] = *(const bf16x8*)(qrow + ks*32 + l4*8);
    }
    bf16x8 onesb;
    #pragma unroll
    for (int i = 0; i < 8; i++) onesb[i] = (short)0x3F80;   // bf16 1.0

    auto stageKV = [&](int ti, int buf) {
        int tw = (ti >= NT) ? ti - NT : ti;
        int kv0 = tw * 64;
        #pragma unroll
        for (int L = 0; L < 4; L++) {
            int c = (wave*4 + L)*64 + lane;
            int krow = c >> 4, kc = c & 15;
            int ksrc = (kc & 8) | ((kc ^ (krow & 7)) & 7);
            gload_lds16(qkv + (size_t)(zb*S_ + kv0 + krow)*LDQ + 2048 + h*DH_ + ksrc*8,
                        (char*)Ks[buf] + c*16);
            int drow = c >> 3, dc = c & 7;
            int dsrc = dc ^ (drow & 7);
            gload_lds16(vT + ((size_t)(h*DH_ + drow)*2 + zb)*S_ + kv0 + dsrc*8,
                        (char*)Vt[buf] + c*16);
        }
    };

    float m_run = -INFINITY;
    f32x4 lsum = (f32x4){0.f, 0.f, 0.f, 0.f};
    f32x4 o[8];
    #pragma unroll
    for (int i = 0; i < 8; i++) o[i] = (f32x4){0.f, 0.f, 0.f, 0.f};

    stageKV(0, 0);
    for (int ti = 0; ti < NT; ti++) {
        int buf = ti & 1;
        int kv0 = ti * 64;
        stageKV(ti + 1, buf ^ 1);
        asm volatile("s_waitcnt vmcnt(8)" ::: "memory");
        __builtin_amdgcn_s_barrier();
        __builtin_amdgcn_sched_barrier(0);
        const char* Kb = (const char*)Ks[buf];
        const char* Vb = (const char*)Vt[buf];

        f32x4 s[4];
        #pragma unroll
        for (int nb = 0; nb < 4; nb++) s[nb] = (f32x4){0.f, 0.f, 0.f, 0.f};
        __builtin_amdgcn_s_setprio(1);
        #pragma unroll
        for (int nb = 0; nb < 4; nb++) {
            int row = nb*16 + lm;
            #pragma unroll
            for (int ks = 0; ks < 4; ks++) {
                bf16x8 bk = *(const bf16x8*)(Kb +
                              ((row*256 + ks*64 + l4*16) ^ ((row & 7) << 4)));
                s[nb] = __builtin_amdgcn_mfma_f32_16x16x32_bf16(aq[ks], bk, s[nb], 0, 0, 0);
            }
        }
        __builtin_amdgcn_s_setprio(0);

        float mk[4];
        #pragma unroll
        for (int nb = 0; nb < 4; nb++) mk[nb] = mask[(size_t)zb*S_ + kv0 + nb*16 + lm];

        // ---- tile-wide max + defer (wave-uniform m) ----
        float pv_[4][4];
        float vmax = -INFINITY;
        #pragma unroll
        for (int r = 0; r < 4; r++)
            #pragma unroll
            for (int nb = 0; nb < 4; nb++) {
                float v = fmaf(s[nb][r], scale, mk[nb]);
                pv_[r][nb] = v;
                vmax = fmaxf(vmax, v);
            }
        vmax = fmaxf(vmax, __shfl_xor(vmax, 1, 64));
        vmax = fmaxf(vmax, __shfl_xor(vmax, 2, 64));
        vmax = fmaxf(vmax, __shfl_xor(vmax, 4, 64));
        vmax = fmaxf(vmax, __shfl_xor(vmax, 8, 64));
        vmax = fmaxf(vmax, __shfl_xor(vmax, 16, 64));
        vmax = fmaxf(vmax, __shfl_xor(vmax, 32, 64));
        if (!__all(vmax - m_run <= 8.0f)) {
            float nm = fmaxf(m_run, vmax);
            float fac = __expf(m_run - nm);
            m_run = nm;
            #pragma unroll
            for (int r = 0; r < 4; r++) lsum[r] *= fac;
            #pragma unroll
            for (int i = 0; i < 8; i++)
                #pragma unroll
                for (int r = 0; r < 4; r++) o[i][r] *= fac;
        }
        #pragma unroll
        for (int r = 0; r < 4; r++)
            #pragma unroll
            for (int nb = 0; nb < 4; nb++)
                pv_[r][nb] = __expf(pv_[r][nb] - m_run);

        // ---- P -> per-wave LDS, XOR-swizzled (write row=l4*4+r: byte ^= l4<<4) ----
        char* Pw = (char*)Ps[wave];
        #pragma unroll
        for (int r = 0; r < 4; r++) {
            int rowb = (l4*4 + r) * 144;
            #pragma unroll
            for (int nb = 0; nb < 4; nb++)
                *(short*)(Pw + rowb + (((nb*16 + lm)*2) ^ (l4 << 4))) =
                    (short)f2bf_rna(pv_[r][nb]);
        }

        // ---- PV + row-sum via ones-MFMA ----
        __builtin_amdgcn_s_setprio(1);
        #pragma unroll
        for (int ks = 0; ks < 2; ks++) {
            bf16x8 ap = *(const bf16x8*)(Pw + lm*144 +
                          ((ks*64 + l4*16) ^ ((lm & 12) << 2)));
            lsum = __builtin_amdgcn_mfma_f32_16x16x32_bf16(ap, onesb, lsum, 0, 0, 0);
            #pragma unroll
            for (int nd = 0; nd < 8; nd++) {
                int d = nd*16 + lm;
                bf16x8 bvv = *(const bf16x8*)(Vb +
                              (((d*128) + ks*64 + l4*16) ^ ((d & 7) << 4)));
                o[nd] = __builtin_amdgcn_mfma_f32_16x16x32_bf16(ap, bvv, o[nd], 0, 0, 0);
            }
        }
        __builtin_amdgcn_s_setprio(0);
        __builtin_amdgcn_s_barrier();
    }
    // drain wrapped prefetch before exit
    asm volatile("s_waitcnt vmcnt(0)" ::: "memory");
    __builtin_amdgcn_s_barrier();

    float inv[4];
    #pragma unroll
    for (int r = 0; r < 4; r++) inv[r] = 1.0f / lsum[r];
    #pragma unroll
    for (int nd = 0; nd < 8; nd++) {
        #pragma unroll
        for (int r = 0; r < 4; r++) {
            size_t row = (size_t)(zb*S_ + q0 + wave*16 + l4*4 + r);
            ctx[row * HD + h*DH_ + nd*16 + lm] = (short)f2bf(o[nd][r] * inv[r]);
        }
    }
}

extern "C" void kernel_launch(void* const* d_in, const int* in_sizes, int n_in,
                              void* d_out, int out_size, void* d_ws, size_t ws_size,
                              hipStream_t stream) {
    const float* x      = (const float*)d_in[0];
    const float* mask   = (const float*)d_in[1];
    const float* ln1_g  = (const float*)d_in[2];
    const float* ln1_b  = (const float*)d_in[3];
    const float* ln2_g  = (const float*)d_in[4];
    const float* ln2_b  = (const float*)d_in[5];
    const float* Wq     = (const float*)d_in[6];
    const float* Wk     = (const float*)d_in[7];
    const float* Wv     = (const float*)d_in[8];
    const float* Wo     = (const float*)d_in[9];
    const float* W1     = (const float*)d_in[10];
    const float* b1     = (const float*)d_in[11];
    const float* W2     = (const float*)d_in[12];
    const float* b2     = (const float*)d_in[13];
    float* out = (float*)d_out;

    char* ws = (char*)d_ws;
    size_t off = 0;
    const size_t WSQ  = (size_t)HD * HD * 2;        // 8 MiB
    const size_t WFF  = (size_t)HD * FF_ * 2;       // 32 MiB
    const size_t ACTB = (size_t)MROWS * HD * 2;     // 16 MiB
    short* WqkvT = (short*)(ws + off); off += 3 * WSQ;             // 24 MiB
    short* WoT   = (short*)(ws + off); off += WSQ;                 // 8
    short* W1T   = (short*)(ws + off); off += WFF;                 // 32
    short* W2T   = (short*)(ws + off); off += WFF;                 // 32
    short* hb    = (short*)(ws + off); off += ACTB;                // 16
    short* qkv   = (short*)(ws + off); off += (size_t)MROWS * LDQ * 2;  // 48
    short* vTb   = (short*)(ws + off); off += (size_t)HD * B_ * S_ * 2; // 16
    short* x1b   = (short*)(ws + off); off += ACTB;                // 16 (bf16 residual)
    short* cb    = WqkvT;   // overlay: ctx over dead WqkvT
    short* act   = qkv;     // overlay: act (64 MiB) over dead qkv+vT

    dim3 blk(256);

    // weight convert+transpose (bf16, [N][K])
    trcvt4_kernel<<<dim3(HD/64, HD/64, 4), blk, 0, stream>>>(Wq, Wk, Wv, Wo, WqkvT, WoT);
    trcvt_kernel<<<dim3(FF_/64, HD/64),  blk, 0, stream>>>(W1, W1T, HD, FF_);
    trcvt_kernel<<<dim3(HD/64,  FF_/64), blk, 0, stream>>>(W2, W2T, FF_, HD);

    // 1) h = LN1(x) -> bf16
    ln_kernel<false><<<MROWS, blk, 0, stream>>>(x, ln1_g, ln1_b, hb);

    // 2) qkv = h @ [Wq|Wk|Wv]  (fused, N=6144); natural order (B L2-resident/XCD)
    gemm128<false,true,false,false,false,false><<<dim3((MROWS/128)*(LDQ/128)), 256, 0, stream>>>(
        hb, WqkvT, nullptr, nullptr, qkv, MROWS, LDQ, HD);

    // 2.5) vT[hd][b][s] = qkv v-part transposed
    vtrans_kernel<<<dim3(HD/32, S_/32, B_), blk, 0, stream>>>(qkv, vTb);

    // 3) ctx = softmax(qk^T*scale + mask) v  -> bf16 (over WqkvT)
    attn_kernel<<<dim3(S_/64, NH_, B_), blk, 0, stream>>>(qkv, vTb, mask, cb);

    // 4) x1 = x + ctx @ Wo  -> bf16; 32x16 grid -> XCD patch
    gemm128<true,true,false,true,false,false><<<dim3((MROWS/128)*(HD/128)), 256, 0, stream>>>(
        cb, WoT, nullptr, x, x1b, MROWS, HD, HD);

    // 5) h2 = LN2(x1) -> bf16 (reuse hb)
    ln_kernel<true><<<MROWS, blk, 0, stream>>>(x1b, ln2_g, ln2_b, hb);

    // 6) act = gelu(h2 @ W1 + b1) -> bf16; natural order
    gemm128<false,true,true,false,false,true><<<dim3((MROWS/128)*(FF_/128)), 256, 0, stream>>>(
        hb, W1T, b1, nullptr, act, MROWS, FF_, HD);

    // 7) out = x1 + act @ W2 + b2  (f32 out, bf16 residual); XCD patch
    gemm128<true,false,true,true,true,false><<<dim3((MROWS/128)*(HD/128)), 256, 0, stream>>>(
        act, W2T, b2, x1b, out, MROWS, HD, FF_);
}